// Round 5
// baseline (321.001 us; speedup 1.0000x reference)
//
#include <hip/hip_runtime.h>
#include <stdint.h>
#include <math.h>

typedef unsigned short u16;
typedef unsigned int u32;
typedef unsigned long long u64;

#define NBW 120
#define NBH 68
#define NTILES (NBW * NBH)       // 8160
#define NPTS 500000
#define EE 12500000              // N * K * K
#define SORT_CAP 768             // max tile entry count ~545 expected; in-place fallback guards
#define NBKT 512                 // distribution-sort buckets
#define HB 512                   // hist blocks (one point per thread)
#define HT 1024                  // hist threads
#define PB 1024                  // expand blocks
#define PT 512                   // expand threads
#define RD_WB 17                 // reduce_diff word-blocks: ceil(DCW/256)
#define RD_CH 16                 // reduce_diff chunks of 32 slices (HB/32)
#define DX 121                   // diff array x dim (0..120)
#define DY 69                    // diff array y dim (0..68)
#define DCELLS 8352              // 121*69 = 8349, padded even
#define DCW (DCELLS / 2)         // packed i16 words per slice

__device__ __forceinline__ int clampi(int v, int lo, int hi) {
    return v < lo ? lo : (v > hi ? hi : v);
}

__device__ __forceinline__ void tile_window(float x, float y, float r,
                                            int& x0, int& x1, int& y0, int& y1) {
    x0 = clampi((int)floorf((x - r) * 0.0625f), 0, NBW);
    x1 = clampi((int)floorf((x + r) * 0.0625f) + 1, 0, NBW);
    y0 = clampi((int)floorf((y - r) * 0.0625f), 0, NBH);
    y1 = clampi((int)floorf((y + r) * 0.0625f) + 1, 0, NBH);
}

// monotone float -> u32 such that ascending u32 == DESCENDING float
__device__ __forceinline__ u32 depth_key(float d) {
    u32 fu = __float_as_uint(d);
    u32 asc = (fu & 0x80000000u) ? ~fu : (fu | 0x80000000u);
    return ~asc;
}
__device__ __forceinline__ float depth_unkey(u32 dk) {
    u32 asc = ~dk;
    u32 fu = (asc & 0x80000000u) ? (asc & 0x7FFFFFFFu) : ~asc;
    return __uint_as_float(fu);
}

// Exactly monotone (in dk) bucket map: table lookup on top-8 bits + integer
// linear interpolation. T is monotone non-decreasing, 0..NBKT.
__device__ __forceinline__ u32 bucket_of(u32 dk, const u32* __restrict__ Ts) {
    u32 k = dk >> 24;
    u32 t0 = Ts[k], t1 = Ts[k + 1];
    u32 b = t0 + (((t1 - t0) * ((dk >> 8) & 0xFFFFu)) >> 16);
    return b >= NBKT ? (NBKT - 1) : b;
}

__device__ __forceinline__ void lds_inc16(u32* arr, int cell) {
    atomicAdd(&arr[cell >> 1], (cell & 1) ? 0x10000u : 1u);
}

// ---- hist: LDS difference-array corners (packed u16 plus/minus -> i16
// slice). Also zeroes sdg (first 9 blocks). One point per thread. ----
__global__ __launch_bounds__(HT) void hist_kernel(const float2* __restrict__ pos,
                                                  const float* __restrict__ rad,
                                                  u32* __restrict__ diffslc,
                                                  int* __restrict__ sdg) {
    __shared__ u32 s_dp[DCW];
    __shared__ u32 s_dm[DCW];
    int tid = threadIdx.x;
    for (int w = tid; w < DCW; w += HT) { s_dp[w] = 0; s_dm[w] = 0; }
    if (blockIdx.x < 9) {
        int j = blockIdx.x * HT + tid;
        if (j < DCELLS) sdg[j] = 0;
    }
    __syncthreads();

    int i = blockIdx.x * HT + tid;
    if (i < NPTS) {
        float2 p = pos[i];
        float r = rad[i];
        int x0, x1, y0, y1;
        tile_window(p.x, p.y, r, x0, x1, y0, y1);
        lds_inc16(s_dp, x0 * DY + y0);
        lds_inc16(s_dp, x1 * DY + y1);
        lds_inc16(s_dm, x0 * DY + y1);
        lds_inc16(s_dm, x1 * DY + y0);
    }
    __syncthreads();

    for (int wi = tid; wi < DCW; wi += HT) {
        u32 pw = s_dp[wi], mw = s_dm[wi];
        int d0 = (int)(pw & 0xFFFFu) - (int)(mw & 0xFFFFu);
        int d1 = (int)(pw >> 16)     - (int)(mw >> 16);
        diffslc[blockIdx.x * DCW + wi] = ((u32)d0 & 0xFFFFu) | ((u32)d1 << 16);
    }
}

// ---- reduce diff slices over HB blocks -> per-cell signed sums ----
// 16 chunks of 32 slices, coalesced loads, atomic combine: 272 blocks.
__global__ void reduce_diff_kernel(const u32* __restrict__ diffslc, int* __restrict__ sdg) {
    int chunk = blockIdx.x / RD_WB;
    int wb    = blockIdx.x % RD_WB;
    int wi = wb * 256 + threadIdx.x;
    if (wi >= DCW) return;
    int a0 = 0, a1 = 0;
    int b0 = chunk * (HB / RD_CH);
    for (int b = b0; b < b0 + HB / RD_CH; ++b) {
        u32 w = diffslc[b * DCW + wi];
        a0 += (int)(short)(w & 0xFFFFu);
        a1 += (int)(short)(w >> 16);
    }
    atomicAdd(&sdg[2 * wi],     a0);
    atomicAdd(&sdg[2 * wi + 1], a1);
}

// 2 parallel blocks: 0 = diff 2D prefix (wave-parallel shfl scans) + entry
// scan -> eo + ecur + out_count; 1 = bucket table -> Tg.
__global__ __launch_bounds__(1024) void scan2_kernel(const int* __restrict__ sdg,
                                                     u32* __restrict__ eo,
                                                     u32* __restrict__ ecur,
                                                     float* __restrict__ out_count,
                                                     u32* __restrict__ Tg) {
    __shared__ int sd[DCELLS];
    __shared__ u32 wsum16[16];
    __shared__ u32 wpre[17];
    __shared__ u32 traw[257];
    int t = threadIdx.x;
    int lane = t & 63;
    int wvid = t >> 6;

    if (blockIdx.x == 0) {
        for (int c = t; c < DCELLS; c += 1024) sd[c] = sdg[c];
        __syncthreads();

        // ---- phase 1: y-prefix per column (one wave per column, shfl scan) ----
        for (int x = wvid; x < DX; x += 16) {
            int idx = x * DY + lane;
            int v = sd[idx];
            for (int off = 1; off < 64; off <<= 1) {
                int n = __shfl_up(v, off, 64);
                if (lane >= off) v += n;
            }
            sd[idx] = v;
            int carry = __shfl(v, 63, 64);
            int y2 = 64 + lane;
            int v2 = (y2 < DY) ? sd[x * DY + y2] : 0;
            for (int off = 1; off < 64; off <<= 1) {
                int n = __shfl_up(v2, off, 64);
                if (lane >= off) v2 += n;
            }
            if (y2 < DY) sd[x * DY + y2] = v2 + carry;
        }
        __syncthreads();

        // ---- phase 2: x-prefix per row (one wave per row, shfl scan) ----
        for (int y = wvid; y < DY; y += 16) {
            int idx = lane * DY + y;
            int v = sd[idx];
            for (int off = 1; off < 64; off <<= 1) {
                int n = __shfl_up(v, off, 64);
                if (lane >= off) v += n;
            }
            sd[idx] = v;
            int carry = __shfl(v, 63, 64);
            int x2 = 64 + lane;
            int v2 = (x2 < DX) ? sd[x2 * DY + y] : 0;
            for (int off = 1; off < 64; off <<= 1) {
                int n = __shfl_up(v2, off, 64);
                if (lane >= off) v2 += n;
            }
            if (x2 < DX) sd[x2 * DY + y] = v2 + carry;
        }
        __syncthreads();

        // ---- entry counts -> exclusive scan over 8160 tiles (wave scan + combine) ----
        int base = t * 8;
        u32 local[8]; u32 sum = 0;
#pragma unroll
        for (int j = 0; j < 8; ++j) {
            int idx = base + j;
            u32 c = 0;
            if (idx < NTILES) {
                int x = idx / NBH, y = idx % NBH;
                c = (u32)sd[x * DY + y];
            }
            local[j] = c; sum += c;
        }
        u32 v = sum;
        for (int off = 1; off < 64; off <<= 1) {
            u32 n = __shfl_up(v, off, 64);
            if (lane >= off) v += n;
        }
        if (lane == 63) wsum16[wvid] = v;
        __syncthreads();
        if (t == 0) {
            u32 run = 0;
            wpre[0] = 0;
#pragma unroll
            for (int w = 0; w < 16; ++w) { run += wsum16[w]; wpre[w + 1] = run; }
        }
        __syncthreads();
        u32 run = wpre[wvid] + v - sum;
#pragma unroll
        for (int j = 0; j < 8; ++j) {
            int idx = base + j;
            if (idx < NTILES) {
                eo[idx] = run;
                ecur[idx] = run;
                out_count[idx] = (float)run;
                run += local[j];
            }
        }
        if (t == 1023) eo[NTILES] = wpre[16];
    } else {
        // ---- bucket table from normal CDF; monotone by running max ----
        if (t < 257) {
            u32 dkb = (u32)t << 24;
            float d = depth_unkey(dkb);
            float u;
            if (d != d) u = (t < 128) ? 0.f : 1.f;
            else {
                float dc = fminf(fmaxf(d, -12.f), 12.f);
                u = 0.5f * erfcf(dc * 0.70710678f);
            }
            traw[t] = (u32)(u * (float)NBKT + 0.5f);
        }
        __syncthreads();
        if (t == 0) {
            u32 run = 0;
            for (int k = 0; k < 257; ++k) {
                u32 v = traw[k];
                if (v > NBKT) v = NBKT;
                if (v > run) run = v;
                Tg[k] = run;
            }
        }
    }
}

// ---- expand: scatter each point to EVERY covered tile, directly at its
// final output position (ecur starts as a copy of eo). One point per
// thread; ~6.6 tiles avg, <=16 max. Per-tile sort canonicalizes order. ----
__global__ __launch_bounds__(PT) void expand_kernel(const float2* __restrict__ pos,
                                                    const float* __restrict__ rad,
                                                    const float* __restrict__ depth,
                                                    u32* __restrict__ ecur,
                                                    float* __restrict__ out_idx,
                                                    float* __restrict__ out_depth) {
    int i = blockIdx.x * PT + threadIdx.x;
    if (i >= NPTS) return;
    float2 p = pos[i];
    float r = rad[i];
    float d = depth[i];
    int x0, x1, y0, y1;
    tile_window(p.x, p.y, r, x0, x1, y0, y1);
    float fpid = (float)i;
    for (int ix = x0; ix < x1; ++ix) {
        int rowb = ix * NBH;
        for (int iy = y0; iy < y1; ++iy) {
            u32 slot = atomicAdd(&ecur[rowb + iy], 1u);
            out_idx[slot]   = fpid;
            out_depth[slot] = d;
        }
    }
}

// One block per tile: tail-fill slice + IN-PLACE per-tile sort: contiguous
// coalesced read of exactly cnt_e entries (no gather, no rejects), bucket
// hist, scan, LDS scatter, per-thread insertion sort per bucket, coalesced
// write-back. LDS ~17.5 KB, 8 blocks/CU (wave cap).
__global__ __launch_bounds__(256) void tile_build_kernel(const u32* __restrict__ eo,
                                                         const u32* __restrict__ Tg,
                                                         float* __restrict__ out_idx,
                                                         float* __restrict__ out_depth) {
    __shared__ u64 keys[SORT_CAP];          // 6 KB  (load order)
    __shared__ u64 keys2[SORT_CAP];         // 6 KB  (bucketed order)
    __shared__ u32 boff[NBKT + 1];          // 2 KB
    __shared__ u32 bcur[NBKT];              // 2 KB
    __shared__ u32 Ts[257];
    __shared__ u32 wsum[4];

    int tid = threadIdx.x;
    int lane = tid & 63;
    int wv = tid >> 6;

    // ---- fused tail fill: [total, EE) of both outputs (covers the diffslc
    // staging region at out_idx tail, long since consumed). ----
    {
        u32 total = eo[NTILES];
        u32 tailn = EE - total;
        u32 per = (tailn + NTILES - 1) / NTILES;
        u64 s = (u64)total + (u64)blockIdx.x * per;
        u64 e = s + per; if (e > (u64)EE) e = EE;
        for (u64 i = s + tid; i < e; i += 256) {
            out_idx[i] = -1.f;
            out_depth[i] = 0.f;
        }
    }

    int t = blockIdx.x;
    u32 base = eo[t];
    int cnt_e = (int)(eo[t + 1] - base);
    if (cnt_e <= 0) return;

    for (int b = tid; b < NBKT; b += 256) boff[b] = 0;
    for (int k = tid; k < 257; k += 256) Ts[k] = Tg[k];
    __syncthreads();

    if (cnt_e <= SORT_CAP) {
        // ---- coalesced load + key pack + bucket hist (no append atomics) ----
        for (int i = tid; i < cnt_e; i += 256) {
            float fi = out_idx[base + i];
            float fd = out_depth[base + i];
            u32 dk = depth_key(fd);
            keys[i] = ((u64)dk << 19) | (u64)(u32)fi;
            atomicAdd(&boff[bucket_of(dk, Ts)], 1u);
        }
        __syncthreads();

        // ---- exclusive scan of 512 buckets (2/thread + shfl scan) ----
        {
            int b0 = tid * 2;
            u32 h0 = boff[b0], h1 = boff[b0 + 1];
            u32 tsum = h0 + h1;
            u32 v = tsum;
            for (int off = 1; off < 64; off <<= 1) {
                u32 n = __shfl_up(v, off, 64);
                if (lane >= off) v += n;
            }
            if (lane == 63) wsum[wv] = v;
            __syncthreads();
            u32 wpre = 0;
            for (int w = 0; w < wv; ++w) wpre += wsum[w];
            u32 run = wpre + v - tsum;
            boff[b0] = run;     bcur[b0] = run;     run += h0;
            boff[b0 + 1] = run; bcur[b0 + 1] = run; run += h1;
            if (tid == 255) boff[NBKT] = run;
        }
        __syncthreads();

        // ---- LDS -> LDS scatter into bucketed order ----
        for (int i = tid; i < cnt_e; i += 256) {
            u64 v = keys[i];
            u32 slot = atomicAdd(&bcur[bucket_of((u32)(v >> 19), Ts)], 1u);
            keys2[slot] = v;
        }
        __syncthreads();

        // ---- per-thread insertion sort of each bucket (u64 = (dk,pid) order) ----
        for (int b = tid; b < NBKT; b += 256) {
            int s = (int)boff[b], e = (int)boff[b + 1];
            for (int i = s + 1; i < e; ++i) {
                u64 k = keys2[i];
                int j = i - 1;
                while (j >= s && keys2[j] > k) { keys2[j + 1] = keys2[j]; --j; }
                keys2[j + 1] = k;
            }
        }
        __syncthreads();

        // ---- decode + coalesced write-back ----
        for (int i = tid; i < cnt_e; i += 256) {
            u64 k = keys2[i];
            out_idx[base + i]   = (float)(u32)(k & 0x7FFFFu);
            out_depth[base + i] = depth_unkey((u32)(k >> 19));
        }
    } else {
        // Statistically unreachable fallback: in-place odd-even sort.
        for (int round = 0; round < cnt_e; ++round) {
            for (int i = (round & 1) + 2 * tid; i + 1 < cnt_e; i += 512) {
                float fi0 = out_idx[base + i], fi1 = out_idx[base + i + 1];
                float fd0 = out_depth[base + i], fd1 = out_depth[base + i + 1];
                u64 k0 = ((u64)depth_key(fd0) << 19) | (u64)(u32)fi0;
                u64 k1 = ((u64)depth_key(fd1) << 19) | (u64)(u32)fi1;
                if (k0 > k1) {
                    out_idx[base + i] = fi1; out_idx[base + i + 1] = fi0;
                    out_depth[base + i] = fd1; out_depth[base + i + 1] = fd0;
                }
            }
            __syncthreads();
        }
    }
}

extern "C" void kernel_launch(void* const* d_in, const int* in_sizes, int n_in,
                              void* d_out, int out_size, void* d_ws, size_t ws_size,
                              hipStream_t stream) {
    (void)in_sizes; (void)n_in; (void)out_size; (void)ws_size;

    const float2* pos  = (const float2*)d_in[0];
    const float* rad   = (const float*)d_in[1];
    const float* depth = (const float*)d_in[2];

    float* out        = (float*)d_out;
    float* out_count  = out;                 // [NTILES]
    float* out_idx    = out + NTILES;        // [EE]
    float* out_depth  = out + NTILES + EE;   // [EE]

    // ws layout (~100 KB)
    u32* eo   = (u32*)d_ws;                  // [NTILES+1]
    u32* ecur = eo + NTILES + 1;             // [NTILES]  running cursors (= eo copy)
    int* sdg  = (int*)(ecur + NTILES);       // [DCELLS]
    u32* Tg   = (u32*)(sdg + DCELLS);        // [257]

    // diffslc (8.6 MB) staged in the guaranteed-dead tail of out_idx (total
    // entries <= 8M of 12.5M since radius < 24 -> window <= 4x4); consumed
    // by reduce_diff before expand/tile_build write anywhere near it, and
    // overwritten by tile_build's tail fill at the end.
    u32* diffslc = (u32*)(out_idx + EE) - (size_t)HB * DCW;

    hist_kernel<<<HB, HT, 0, stream>>>(pos, rad, diffslc, sdg);
    reduce_diff_kernel<<<RD_CH * RD_WB, 256, 0, stream>>>(diffslc, sdg);
    scan2_kernel<<<2, 1024, 0, stream>>>(sdg, eo, ecur, out_count, Tg);
    expand_kernel<<<PB, PT, 0, stream>>>(pos, rad, depth, ecur, out_idx, out_depth);
    tile_build_kernel<<<NTILES, 256, 0, stream>>>(eo, Tg, out_idx, out_depth);
}